// Round 4
// baseline (895.529 us; speedup 1.0000x reference)
//
#include <hip/hip_runtime.h>
#include <hip/hip_bf16.h>

constexpr int kNodes = 1000000;
constexpr int kEdges = 32000000;

// ---------------- Tile-sorted scatter path ----------------
// 256 buckets x 4096 nodes. Record u32 = (node&4095)<<20 | q20,
// q20 = clamp(round((orc_other+1)*2^19), 0, 0xFFFFF)  (error <= 2^-20).
// Tiles of 4096 edges (8192 records) counting-sorted by bucket in LDS;
// per-bucket counts padded to x4 records (16B) so segments are int4-aligned;
// pad slots = 0xFFFFFFFF. Tile flushed coalesced to rec[tile*TSTRIDE].
// Per-(bucket,tile) u16 start offsets in [bucket][tile] layout (row NB =
// padded tile total).
constexpr int NB = 256;
constexpr int BSHIFT = 12;
constexpr int BNODES = 4096;
constexpr int NBUSED = (kNodes + BNODES - 1) / BNODES;   // 245
constexpr int EPT = 4096;
constexpr int TILES = (kEdges + EPT - 1) / EPT;          // 7813
constexpr int TSTRIDE = 8960;            // 2*EPT + 256*3, mult of 4
constexpr int SSPLIT = 4;                // sub-blocks per bucket in accum
constexpr int TPS = (TILES + SSPLIT - 1) / SSPLIT;       // 1954

constexpr size_t kRecBytes = (size_t)TILES * TSTRIDE * 4;        // ~280 MB
constexpr size_t kTblOff   = kRecBytes;
constexpr size_t kTblBytes = ((size_t)(NB + 1) * TILES * 2 + 15) & ~(size_t)15;
constexpr size_t kAccOff   = kTblOff + kTblBytes;                // 16B aligned
constexpr size_t kWsNeeded = kAccOff + (size_t)SSPLIT * kNodes * 8;  // ~316 MB

__global__ __launch_bounds__(512, 8) void scatter_sort(
        const int* __restrict__ ei, const float* __restrict__ orc,
        unsigned* __restrict__ rec, unsigned short* __restrict__ tbl) {
    __shared__ alignas(16) unsigned reorder[TSTRIDE];  // 35 KB
    __shared__ unsigned cnt[NB];                 // hist -> rank cursor
    __shared__ unsigned scanbuf[NB];             // inclusive scan (padded)
    const int tid = threadIdx.x;
    const int t = blockIdx.x;
    const int e0 = t * EPT;
    const int ne = min(EPT, kEdges - e0);        // 4096; last tile 2048 (x4)

    for (int k = tid; k < NB; k += 512) cnt[k] = 0u;
    for (int k = tid; k < TSTRIDE; k += 512) reorder[k] = 0xFFFFFFFFu;
    __syncthreads();

    // phase 1: coalesced edge read -> bucket histogram (edges stay in L2)
    for (int k4 = tid * 4; k4 < ne; k4 += 2048) {
        const int4 s4 = *reinterpret_cast<const int4*>(ei + e0 + k4);
        const int4 d4 = *reinterpret_cast<const int4*>(ei + kEdges + e0 + k4);
        atomicAdd(&cnt[s4.x >> BSHIFT], 1u);
        atomicAdd(&cnt[s4.y >> BSHIFT], 1u);
        atomicAdd(&cnt[s4.z >> BSHIFT], 1u);
        atomicAdd(&cnt[s4.w >> BSHIFT], 1u);
        atomicAdd(&cnt[d4.x >> BSHIFT], 1u);
        atomicAdd(&cnt[d4.y >> BSHIFT], 1u);
        atomicAdd(&cnt[d4.z >> BSHIFT], 1u);
        atomicAdd(&cnt[d4.w >> BSHIFT], 1u);
    }
    __syncthreads();

    // phase 2: Hillis-Steele inclusive scan of padded counts
    if (tid < NB) scanbuf[tid] = (cnt[tid] + 3u) & ~3u;
    __syncthreads();
    for (int off = 1; off < NB; off <<= 1) {
        unsigned v = 0u;
        if (tid < NB && tid >= off) v = scanbuf[tid - off];
        __syncthreads();
        if (tid < NB) scanbuf[tid] += v;
        __syncthreads();
    }
    if (tid < NB) {
        const unsigned pc = (cnt[tid] + 3u) & ~3u;
        const unsigned st = scanbuf[tid] - pc;
        tbl[(size_t)tid * TILES + t] = (unsigned short)st;
        cnt[tid] = st;                            // becomes rank cursor
    }
    if (tid == 0) tbl[(size_t)NB * TILES + t] = (unsigned short)scanbuf[NB - 1];
    __syncthreads();

    // phase 3: re-read edges (L2-hot), rank, build records in reorder buffer
    for (int k4 = tid * 4; k4 < ne; k4 += 2048) {
        const int4 s4 = *reinterpret_cast<const int4*>(ei + e0 + k4);
        const int4 d4 = *reinterpret_cast<const int4*>(ei + kEdges + e0 + k4);
        const int ss[4] = {s4.x, s4.y, s4.z, s4.w};
        const int dd[4] = {d4.x, d4.y, d4.z, d4.w};
        float osv[4], odv[4];
        #pragma unroll
        for (int j = 0; j < 4; ++j) { osv[j] = orc[ss[j]]; odv[j] = orc[dd[j]]; }
        #pragma unroll
        for (int j = 0; j < 4; ++j) {
            unsigned qs = __float2uint_rn((odv[j] + 1.0f) * 524288.0f);
            unsigned qd = __float2uint_rn((osv[j] + 1.0f) * 524288.0f);
            qs = qs > 0xFFFFFu ? 0xFFFFFu : qs;
            qd = qd > 0xFFFFFu ? 0xFFFFFu : qd;
            const int s = ss[j], d = dd[j];
            const unsigned rs = atomicAdd(&cnt[s >> BSHIFT], 1u);
            reorder[rs] = ((unsigned)(s & (BNODES - 1)) << 20) | qs;
            const unsigned rd = atomicAdd(&cnt[d >> BSHIFT], 1u);
            reorder[rd] = ((unsigned)(d & (BNODES - 1)) << 20) | qd;
        }
    }
    __syncthreads();

    // phase 4: coalesced full-line flush
    const unsigned total = scanbuf[NB - 1];       // padded, mult of 4
    unsigned* __restrict__ g = rec + (size_t)t * TSTRIDE;
    for (unsigned k = tid * 4; k < total; k += 2048)
        *reinterpret_cast<int4*>(g + k) = *reinterpret_cast<const int4*>(reorder + k);
}

// grid (NBUSED, SSPLIT): block (b,s) accumulates tiles [s*TPS, (s+1)*TPS)
// of bucket b into partial acc[s][node]. Packed u64: deg<<42 | sum(q20);
// partials add exactly (deg < 2^22, sum < 2^42 -> no cross-field carries).
__global__ __launch_bounds__(512, 8) void bucket_accum(
        const unsigned* __restrict__ rec, const unsigned short* __restrict__ tbl,
        unsigned long long* __restrict__ acc) {
    __shared__ unsigned long long lacc[BNODES];   // 32 KB
    const int b = blockIdx.x;
    const int s = blockIdx.y;
    const int tid = threadIdx.x;
    for (int k = tid; k < BNODES; k += 512) lacc[k] = 0ull;
    __syncthreads();
    const int t0 = s * TPS;
    const int t1 = min(t0 + TPS, TILES);
    const unsigned short* __restrict__ r0 = tbl + (size_t)b * TILES;
    const unsigned short* __restrict__ r1 = tbl + (size_t)(b + 1) * TILES;
    for (int t = t0 + tid; t < t1; t += 512) {
        const unsigned st = r0[t];
        const unsigned en = r1[t];
        const uint4* __restrict__ p =
            reinterpret_cast<const uint4*>(rec + (size_t)t * TSTRIDE + st);
        const unsigned n4 = (en - st) >> 2;
        for (unsigned i = 0; i < n4; ++i) {
            const uint4 v = p[i];
            const unsigned long long a0 = (v.x == 0xFFFFFFFFu) ? 0ull
                : ((1ull << 42) | (unsigned long long)(v.x & 0xFFFFFu));
            atomicAdd(&lacc[v.x >> 20], a0);
            const unsigned long long a1 = (v.y == 0xFFFFFFFFu) ? 0ull
                : ((1ull << 42) | (unsigned long long)(v.y & 0xFFFFFu));
            atomicAdd(&lacc[v.y >> 20], a1);
            const unsigned long long a2 = (v.z == 0xFFFFFFFFu) ? 0ull
                : ((1ull << 42) | (unsigned long long)(v.z & 0xFFFFFu));
            atomicAdd(&lacc[v.z >> 20], a2);
            const unsigned long long a3 = (v.w == 0xFFFFFFFFu) ? 0ull
                : ((1ull << 42) | (unsigned long long)(v.w & 0xFFFFFu));
            atomicAdd(&lacc[v.w >> 20], a3);
        }
    }
    __syncthreads();
    unsigned long long* __restrict__ ap = acc + (size_t)s * kNodes;
    const int base = b << BSHIFT;
    for (int k = tid; k < BNODES; k += 512) {
        const int n = base + k;
        if (n < kNodes) ap[n] = lacc[k];
    }
}

// ---------------- Fallback (atomic) path ----------------
constexpr float kScale = 1048576.0f;           // 2^20
constexpr float kInvScale = 1.0f / 1048576.0f;
constexpr long long kBias = 1ll << 36;

__global__ __launch_bounds__(256) void zero_acc(unsigned long long* __restrict__ acc) {
    int i = blockIdx.x * 256 + threadIdx.x;
    if (i < kNodes) acc[i] = 0ull;
}

__global__ __launch_bounds__(256) void edge_kernel(
        const int* __restrict__ ei,
        const float* __restrict__ orc,
        unsigned long long* __restrict__ acc) {
    int t = blockIdx.x * 256 + threadIdx.x;
    int e0 = t * 4;
    if (e0 >= kEdges) return;
    const int4 s4 = *reinterpret_cast<const int4*>(ei + e0);
    const int4 d4 = *reinterpret_cast<const int4*>(ei + kEdges + e0);
    const int ss[4] = {s4.x, s4.y, s4.z, s4.w};
    const int dd[4] = {d4.x, d4.y, d4.z, d4.w};
    #pragma unroll
    for (int k = 0; k < 4; ++k) {
        const float os = orc[ss[k]];
        const float od = orc[dd[k]];
        const unsigned long long ps =
            (1ull << 48) + (unsigned long long)(kBias + (long long)__float2ll_rn(od * kScale));
        const unsigned long long pd =
            (1ull << 48) + (unsigned long long)(kBias + (long long)__float2ll_rn(os * kScale));
        atomicAdd(&acc[ss[k]], ps);
        atomicAdd(&acc[dd[k]], pd);
    }
}

// ---------------- Node phase ----------------
// MODE 0: single acc, deg<<48 | biased 2^20 sum.
// MODE 2: SSPLIT partial accs, deg<<42 | sum(q20).
// Harmonics: hw v_sin/v_cos on revolutions (rev = n/2 in [0,0.5]) + angle-
// addition recurrences for k=2..4 (few-ulp error, well under threshold).
template <int MODE>
__global__ __launch_bounds__(256) void node_kernel(
        const float* __restrict__ orc,
        const unsigned long long* __restrict__ acc,
        const float* __restrict__ W1, const float* __restrict__ b1,
        const float* __restrict__ W2, const float* __restrict__ b2,
        const float* __restrict__ gamma, const float* __restrict__ beta,
        float* __restrict__ out) {
    const int i = blockIdx.x * 256 + threadIdx.x;
    if (i >= kNodes) return;

    const float x0 = orc[i];
    float n1;   // normalized neighbor-mean in [0,1]
    if (MODE == 0) {
        const unsigned long long p = acc[i];
        const unsigned deg = (unsigned)(p >> 48);
        const long long sf = (long long)(p & ((1ull << 48) - 1)) - (long long)deg * kBias;
        const float nb = (deg > 0) ? ((float)sf * kInvScale) / (float)deg : 0.0f;
        n1 = __saturatef((nb + 1.0f) * 0.5f);
    } else {
        unsigned long long p = acc[i];
        #pragma unroll
        for (int s = 1; s < SSPLIT; ++s) p += acc[(size_t)s * kNodes + i];
        const unsigned deg = (unsigned)(p >> 42);
        const unsigned long long sumq = p & ((1ull << 42) - 1);
        // n1 = ((sumq/2^19)/deg - 1 + 1)/2 = sumq / (deg * 2^20); q<2^20 -> <1
        n1 = (deg > 0) ? __fdividef((float)sumq, (float)deg * 1048576.0f) : 0.5f;
    }
    const float n0 = __saturatef((x0 + 1.0f) * 0.5f);

    float Phi[16];
    {
        const float s1 = __builtin_amdgcn_sinf(n0 * 0.5f);  // sin(pi*n0)
        const float c1 = __builtin_amdgcn_cosf(n0 * 0.5f);
        const float s2 = 2.0f * s1 * c1, c2 = fmaf(-2.0f * s1, s1, 1.0f);
        const float s3 = s1 * c2 + c1 * s2, c3 = c1 * c2 - s1 * s2;
        const float s4 = 2.0f * s2 * c2, c4 = fmaf(-2.0f * s2, s2, 1.0f);
        Phi[0] = s1; Phi[1] = c1; Phi[2] = s2; Phi[3] = c2;
        Phi[4] = s3; Phi[5] = c3; Phi[6] = s4; Phi[7] = c4;
    }
    {
        const float s1 = __builtin_amdgcn_sinf(n1 * 0.5f);  // sin(pi*n1)
        const float c1 = __builtin_amdgcn_cosf(n1 * 0.5f);
        const float s2 = 2.0f * s1 * c1, c2 = fmaf(-2.0f * s1, s1, 1.0f);
        const float s3 = s1 * c2 + c1 * s2, c3 = c1 * c2 - s1 * s2;
        const float s4 = 2.0f * s2 * c2, c4 = fmaf(-2.0f * s2, s2, 1.0f);
        Phi[8] = s1; Phi[9] = c1; Phi[10] = s2; Phi[11] = c2;
        Phi[12] = s3; Phi[13] = c3; Phi[14] = s4; Phi[15] = c4;
    }

    float y[16];
    #pragma unroll
    for (int d = 0; d < 16; ++d) y[d] = b2[d];
    #pragma unroll
    for (int j = 0; j < 32; ++j) {
        float a = b1[j];
        #pragma unroll
        for (int d = 0; d < 16; ++d) a = fmaf(Phi[d], W1[j * 16 + d], a);
        a = fmaxf(a, 0.0f);
        #pragma unroll
        for (int d = 0; d < 16; ++d) y[d] = fmaf(a, W2[d * 32 + j], y[d]);
    }

    float mu = 0.0f;
    #pragma unroll
    for (int d = 0; d < 16; ++d) mu += y[d];
    mu *= (1.0f / 16.0f);
    float var = 0.0f;
    #pragma unroll
    for (int d = 0; d < 16; ++d) { const float t = y[d] - mu; var = fmaf(t, t, var); }
    var *= (1.0f / 16.0f);
    const float inv = rsqrtf(var + 1e-5f);

    float4* o4 = reinterpret_cast<float4*>(out + (size_t)i * 16);
    #pragma unroll
    for (int q = 0; q < 4; ++q) {
        float4 o;
        o.x = (y[4 * q + 0] - mu) * inv * gamma[4 * q + 0] + beta[4 * q + 0] + Phi[4 * q + 0];
        o.y = (y[4 * q + 1] - mu) * inv * gamma[4 * q + 1] + beta[4 * q + 1] + Phi[4 * q + 1];
        o.z = (y[4 * q + 2] - mu) * inv * gamma[4 * q + 2] + beta[4 * q + 2] + Phi[4 * q + 2];
        o.w = (y[4 * q + 3] - mu) * inv * gamma[4 * q + 3] + beta[4 * q + 3] + Phi[4 * q + 3];
        o4[q] = o;
    }
}

extern "C" void kernel_launch(void* const* d_in, const int* in_sizes, int n_in,
                              void* d_out, int out_size, void* d_ws, size_t ws_size,
                              hipStream_t stream) {
    const float* orc   = (const float*)d_in[0];
    const int*   ei    = (const int*)d_in[1];
    const float* W1    = (const float*)d_in[2];
    const float* b1    = (const float*)d_in[3];
    const float* W2    = (const float*)d_in[4];
    const float* b2    = (const float*)d_in[5];
    const float* gamma = (const float*)d_in[6];
    const float* beta  = (const float*)d_in[7];
    float* out = (float*)d_out;
    char* ws = (char*)d_ws;

    if (ws_size >= kWsNeeded) {
        unsigned* rec = (unsigned*)ws;
        unsigned short* tbl = (unsigned short*)(ws + kTblOff);
        unsigned long long* acc = (unsigned long long*)(ws + kAccOff);
        scatter_sort<<<TILES, 512, 0, stream>>>(ei, orc, rec, tbl);
        bucket_accum<<<dim3(NBUSED, SSPLIT), 512, 0, stream>>>(rec, tbl, acc);
        node_kernel<2><<<(kNodes + 255) / 256, 256, 0, stream>>>(
            orc, acc, W1, b1, W2, b2, gamma, beta, out);
    } else {
        unsigned long long* acc = (unsigned long long*)ws;  // 8 MB
        zero_acc<<<(kNodes + 255) / 256, 256, 0, stream>>>(acc);
        edge_kernel<<<(kEdges / 4 + 255) / 256, 256, 0, stream>>>(ei, orc, acc);
        node_kernel<0><<<(kNodes + 255) / 256, 256, 0, stream>>>(
            orc, acc, W1, b1, W2, b2, gamma, beta, out);
    }
}